// Round 7
// baseline (647.159 us; speedup 1.0000x reference)
//
#include <hip/hip_runtime.h>
#include <hip/hip_bf16.h>
#include <math.h>
#include <stdint.h>

typedef __hip_bfloat16 bf16;

__device__ __forceinline__ float b2f(bf16 v){ return __bfloat162float(v); }
__device__ __forceinline__ bf16  f2b(float v){ return __float2bfloat16(v); }
__device__ __forceinline__ float gelu_f(float x){ return 0.5f*x*(1.0f+erff(x*0.70710678118654752f)); }

// fp8 e4m3 (OCP on gfx950) via HW converts; store value*16 to stay in normal range
#define SC8  16.0f
#define ISC8 0.0625f
__device__ __forceinline__ uint8_t f2e4(float v){
  int r = __builtin_amdgcn_cvt_pk_fp8_f32(v*SC8, v*SC8, 0, false);
  return (uint8_t)(r & 0xFF);
}
__device__ __forceinline__ float e42f(uint8_t b){
  return __builtin_amdgcn_cvt_f32_fp8((int)b, 0) * ISC8;
}

// MFMA types: gfx950 v_mfma_f32_16x16x32_bf16 takes 8 x __bf16 vectors (LLVM V8y)
typedef __bf16 bf16x8 __attribute__((ext_vector_type(8)));
typedef float  f32x4  __attribute__((ext_vector_type(4)));
typedef short  v8s    __attribute__((ext_vector_type(8)));
union Frag { bf16x8 v; unsigned short u[8]; };

__device__ __forceinline__ unsigned short bfb(float v){
  union { bf16 h; unsigned short u; } cv; cv.h = f2b(v); return cv.u;
}
__device__ __forceinline__ float bfu2f(unsigned short u){
  union { float f; unsigned u32; } x; x.u32 = ((unsigned)u) << 16; return x.f;
}
__device__ __forceinline__ bf16x8 ldsb8(const short* p){
  return *reinterpret_cast<const bf16x8*>(p);
}
// k_tr internal LDS swizzle (multiple of 8 -> preserves in-order 8-ci chunks)
__device__ __forceinline__ int SW8(int w){ return ((w ^ (w >> 3)) & 7) << 3; }

// ---- problem constants: B=16, C=64, H=W=160, HW=25600, E=4, L=5 ----
// ---- ALL inputs/outputs are FLOAT32 (per reference setup_inputs). ----
// ---- ZERO d_ws usage. Scratch: d_out (104,857,600 B) + x-buffer (104,857,600 B).

// K_TR: x (NCHW f32) -> xT (NHWC bf16). Block = (b,h). LDS transpose.
__global__ __launch_bounds__(256) void k_tr(const float* __restrict__ x,
                                            bf16* __restrict__ xT){
  __shared__ __align__(16) short LT[160*64];   // [w][ci^SW8(w)]  (40,960 B)
  int bid = blockIdx.x;
  int h = bid % 160;
  int b = bid / 160;
  int tid = threadIdx.x;
  // stage-in: 1280 pair-quads: (ci0 even, w4): read 2 float4, pack 4 b32 writes
  #pragma unroll
  for (int i=0;i<5;i++){
    int q = tid + i*256;               // < 1280 always
    int ci0 = (q/40)*2;
    int w4  = (q - (q/40)*40)*4;
    const float* pa = x + (((b*64 + ci0)*160 + h)*160) + w4;
    float4 fa = *reinterpret_cast<const float4*>(pa);
    float4 fb = *reinterpret_cast<const float4*>(pa + 25600);
    float va[4] = {fa.x, fa.y, fa.z, fa.w};
    float vb[4] = {fb.x, fb.y, fb.z, fb.w};
    #pragma unroll
    for (int j=0;j<4;j++){
      int w = w4 + j;
      unsigned pk = (unsigned)bfb(va[j]) | ((unsigned)bfb(vb[j]) << 16);
      int slot = w*64 + (ci0 ^ SW8(w));
      *reinterpret_cast<unsigned*>(&LT[slot]) = pk;
    }
  }
  __syncthreads();
  // stage-out: 1280 chunks (w, ci0 mult 8): b128 LDS read -> b128 global store
  bf16* dst = xT + ((size_t)(b*160 + h))*160*64;
  #pragma unroll
  for (int i=0;i<5;i++){
    int k = tid + i*256;               // < 1280
    int w = k >> 3;
    int ci0 = (k & 7) << 3;
    v8s v = *reinterpret_cast<const v8s*>(&LT[w*64 + (ci0 ^ SW8(w))]);
    *reinterpret_cast<v8s*>(dst + w*64 + ci0) = v;
  }
}

// K_ZERO: zero meanX (1024 f32). No runtime APIs in kernel_launch (graph-capture).
__global__ __launch_bounds__(256) void k_zero(float* __restrict__ p){
  p[blockIdx.x*256 + threadIdx.x] = 0.f;
}

// K1: FUSED 3x3 conv (64->64)+bias+gelu -> 1x1 conv (64->128)+bias + shuffle split,
// as implicit-GEMM bf16 MFMA (16x16x32). Block = (b, h, half-row of 80 px), 4 waves.
// BYTE-IDENTICAL to the round-4 kernel that measured 197 us / passed.
__global__ __launch_bounds__(256) void k_conv12(const bf16* __restrict__ xT,
                                                const float* __restrict__ w1,
                                                const float* __restrict__ b1,
                                                const float* __restrict__ w2,
                                                const float* __restrict__ b2,
                                                bf16* __restrict__ xs0,
                                                bf16* __restrict__ k0){
  __shared__ __align__(16) short Xs[16128];   // 3*84*64  (32,256 B)
  __shared__ __align__(16) short H1[5120];    // 80*64    (10,240 B)
  int bid = blockIdx.x;
  int half = bid & 1;
  int bh = bid >> 1;
  int h = bh % 160;
  int b = bh / 160;
  int w0 = half*80;
  int tid = threadIdx.x;
  int lane = tid & 63;
  int wv = tid >> 6;
  int c = lane & 15;     // pixel-in-group / A-row
  int g = lane >> 4;     // k-group

  // ---- conv1 A-frags: gather 18 frags x 8 elems from w1 (stride-9, L2-hit) ----
  Frag wf[18];
  {
    int co = wv*16 + c;
    const float* wbase = w1 + co*576 + g*72;   // + kk*288 + e*9 + r*3 + s
    #pragma unroll
    for (int r=0;r<3;r++){
      #pragma unroll
      for (int s=0;s<3;s++){
        #pragma unroll
        for (int kk=0;kk<2;kk++){
          Frag f;
          #pragma unroll
          for (int e=0;e<8;e++)
            f.u[e] = bfb(wbase[kk*288 + e*9 + r*3 + s]);
          wf[(r*3+s)*2+kk] = f;
        }
      }
    }
  }

  // ---- stage X from xT: 2016 b128 chunks (3 rows x 84 cols x 8 ci-chunks) ----
  {
    const bf16* xTb = xT + (size_t)b*160*160*64;
    #pragma unroll
    for (int it=0; it<8; ++it){
      int q = tid + it*256;
      if (q < 2016){
        int r   = q / 672;
        int rem = q - r*672;
        int col = rem >> 3;
        int ci0 = (rem & 7) << 3;
        int gh  = h - 1 + r;
        int gw  = w0 - 1 + col;
        v8s val = {0,0,0,0,0,0,0,0};
        if ((unsigned)gh < 160u && (unsigned)gw < 160u)
          val = *reinterpret_cast<const v8s*>(xTb + (gh*160 + gw)*64 + ci0);
        int eidx = (r*84 + col)*64 + (ci0 ^ ((col & 7) << 3));
        *reinterpret_cast<v8s*>(&Xs[eidx]) = val;
      }
    }
  }
  __syncthreads();

  // ---- conv1: 9 per-tap GEMMs, K=64 (2 halves) -> gelu -> H1 ----
  float bb1r[4];
  {
    const float* bp = b1 + wv*16 + g*4;
    #pragma unroll
    for (int r=0;r<4;r++) bb1r[r] = bp[r];
  }
  int bB[3][2];
  #pragma unroll
  for (int s=0;s<3;s++){
    #pragma unroll
    for (int kk=0;kk<2;kk++)
      bB[s][kk] = (c + s)*64 + ((kk*32 + g*8) ^ (((c + s) & 7) << 3));
  }
  #pragma unroll 1
  for (int n=0;n<5;++n){
    f32x4 acc0 = {0.f,0.f,0.f,0.f};
    f32x4 acc1 = {0.f,0.f,0.f,0.f};
    #pragma unroll
    for (int r=0;r<3;r++){
      #pragma unroll
      for (int s=0;s<3;s++){
        int base = r*5376 + n*1024;
        bf16x8 bf0 = ldsb8(&Xs[bB[s][0] + base]);
        bf16x8 bf1 = ldsb8(&Xs[bB[s][1] + base]);
        int t = (r*3 + s)*2;
        acc0 = __builtin_amdgcn_mfma_f32_16x16x32_bf16(wf[t].v,   bf0, acc0, 0, 0, 0);
        acc1 = __builtin_amdgcn_mfma_f32_16x16x32_bf16(wf[t+1].v, bf1, acc1, 0, 0, 0);
      }
    }
    // D: lane -> px = n*16+c, ch = 16wv + 4g + r
    unsigned long long pk = 0ull;
    #pragma unroll
    for (int r=0;r<4;r++){
      float v = gelu_f(acc0[r] + acc1[r] + bb1r[r]);
      pk |= ((unsigned long long)bfb(v)) << (16*r);
    }
    int eH = (n*16 + c)*64 + ((wv*16 + g*4) ^ ((c & 7) << 3));
    *reinterpret_cast<unsigned long long*>(&H1[eH]) = pk;
  }
  __syncthreads();

  // ---- conv2: 1x1, K=64, wave owns out ch [32wv,32wv+32), shuffle-split store ----
  Frag w2f[4];
  {
    #pragma unroll
    for (int j=0;j<2;j++){
      #pragma unroll
      for (int kk=0;kk<2;kk++){
        const float* wp = w2 + (wv*32 + j*16 + c)*64 + kk*32 + g*8;
        Frag f;
        #pragma unroll
        for (int e=0;e<8;e++) f.u[e] = bfb(wp[e]);
        w2f[j*2+kk] = f;
      }
    }
  }
  float bb2r[2][4];
  #pragma unroll
  for (int j=0;j<2;j++){
    const float* bp = b2 + wv*32 + j*16 + g*4;
    #pragma unroll
    for (int r=0;r<4;r++) bb2r[j][r] = bp[r];
  }
  // hoisted store bases: o -> shuffled ch -> xs0/k0 base (wave-uniform split per j)
  int posb = h*160 + w0 + c;
  int sb[2][4]; int flg[2][4];
  #pragma unroll
  for (int j=0;j<2;j++){
    #pragma unroll
    for (int r=0;r<4;r++){
      int o = wv*32 + j*16 + g*4 + r;
      int n2 = ((o & 63) << 1) | (o >> 6);
      if (n2 < 64){ sb[j][r] = (b*64 + n2)*25600 + posb;        flg[j][r] = 1; }
      else        { sb[j][r] = (b*64 + (n2-64))*25600 + posb;   flg[j][r] = 0; }
    }
  }
  int bH0 = c*64 + ((g*8)      ^ ((c & 7) << 3));
  int bH1 = c*64 + ((32 + g*8) ^ ((c & 7) << 3));
  #pragma unroll 1
  for (int n=0;n<5;++n){
    bf16x8 h0 = ldsb8(&H1[bH0 + n*1024]);
    bf16x8 h1 = ldsb8(&H1[bH1 + n*1024]);
    #pragma unroll
    for (int j=0;j<2;j++){
      f32x4 acc = {0.f,0.f,0.f,0.f};
      acc = __builtin_amdgcn_mfma_f32_16x16x32_bf16(w2f[j*2].v,   h0, acc, 0, 0, 0);
      acc = __builtin_amdgcn_mfma_f32_16x16x32_bf16(w2f[j*2+1].v, h1, acc, 0, 0, 0);
      #pragma unroll
      for (int r=0;r<4;r++){
        float v = acc[r] + bb2r[j][r];
        bf16 bv = f2b(v);
        if (flg[j][r]) xs0[sb[j][r] + n*16] = bv;
        else           k0 [sb[j][r] + n*16] = bv;
      }
    }
  }
}

// K3: separable depthwise (1x3 then 3x1) + gelu, 8 px/thread, FUSED mean:
// every wave is bc-uniform (3200 px/bc = 50 waves) -> shfl-reduce + 1 atomic/wave.
__global__ __launch_bounds__(256) void k_sc(const bf16* __restrict__ xs0,
                                            const float* __restrict__ scw1,
                                            const float* __restrict__ scb1,
                                            const float* __restrict__ scw2,
                                            const float* __restrict__ scb2,
                                            bf16* __restrict__ xsf,
                                            float* __restrict__ meanX){
  int t = blockIdx.x*256 + threadIdx.x;       // 3,276,800 total
  int w8 = (t % 20) * 8;
  int r2 = t / 20;
  int h  = r2 % 160;
  int bc = r2 / 160;
  int c  = bc & 63;
  const bf16* plane = xs0 + (size_t)bc*25600;
  float w1a = scw1[c*3], w1b = scw1[c*3+1], w1c = scw1[c*3+2];
  float b1  = scb1[c];
  float w2a = scw2[c*3], w2b = scw2[c*3+1], w2c = scw2[c*3+2];
  float b2v = scb2[c];
  float acc[8];
  #pragma unroll
  for (int j=0;j<8;j++) acc[j] = b2v;
  #pragma unroll
  for (int dh=0; dh<3; dh++){
    int hh = h-1+dh;
    if ((unsigned)hh < 160u){
      const bf16* row = plane + hh*160;
      float wnd[10];
      v8s mv = *reinterpret_cast<const v8s*>(row + w8);
      #pragma unroll
      for (int j=0;j<8;j++) wnd[j+1] = bfu2f((unsigned short)mv[j]);
      wnd[0] = (w8 > 0)   ? b2f(row[w8-1]) : 0.f;
      wnd[9] = (w8 < 152) ? b2f(row[w8+8]) : 0.f;
      float w2h = (dh==0)?w2a:((dh==1)?w2b:w2c);
      #pragma unroll
      for (int j=0;j<8;j++){
        float inner = fmaf(w1a, wnd[j], fmaf(w1b, wnd[j+1], fmaf(w1c, wnd[j+2], b1)));
        acc[j] = fmaf(w2h, inner, acc[j]);
      }
    }
  }
  v8s o;
  float ls = 0.f;
  #pragma unroll
  for (int j=0;j<8;j++){
    unsigned short ub = bfb(gelu_f(acc[j]));
    o[j] = (short)ub;
    ls += bfu2f(ub);            // sum the bf16-rounded value (matches old k_mean)
  }
  *reinterpret_cast<v8s*>(xsf + (size_t)bc*25600 + h*160 + w8) = o;
  // wave reduction (bc uniform across the wave: 3200 threads per bc, 3200%64==0)
  #pragma unroll
  for (int off=32; off>0; off>>=1) ls += __shfl_down(ls, off);
  if ((threadIdx.x & 63) == 0) atomicAdd(&meanX[bc], ls*(1.0f/25600.0f));
}

// K4: fused k-branch: agg(160->41) -> agg(41->11) -> caldw(3x3 on 11x11).
// Block = one (b,c) plane; whole plane staged in LDS; A1/A2 never touch HBM.
__global__ __launch_bounds__(256) void k_aggfuse(const bf16* __restrict__ k0,
                                                 const float* __restrict__ aggw,
                                                 const float* __restrict__ aggb,
                                                 const float* __restrict__ dww,
                                                 const float* __restrict__ dwb,
                                                 float* __restrict__ T1){
  __shared__ __align__(16) short KP[25600];   // 51,200 B
  __shared__ float A1L[1681];                 //  6,724 B
  __shared__ float A2L[121];                  //    484 B
  int bc = blockIdx.x;
  int c = bc & 63;
  int tid = threadIdx.x;
  const bf16* src = k0 + (size_t)bc*25600;
  for (int i=tid; i<3200; i+=256)
    *reinterpret_cast<v8s*>(&KP[i*8]) = *reinterpret_cast<const v8s*>(src + i*8);
  float wgt[16];
  #pragma unroll
  for (int q=0;q<16;q++) wgt[q] = aggw[c*16+q];
  float bia = aggb[c];
  __syncthreads();
  for (int i=tid; i<1681; i+=256){
    int oh = i/41, ow = i - oh*41;
    float acc = bia;
    #pragma unroll
    for (int kh=0;kh<4;kh++){
      int ih = oh*4-2+kh;
      if ((unsigned)ih < 160u){
        #pragma unroll
        for (int kw=0;kw<4;kw++){
          int iw = ow*4-2+kw;
          if ((unsigned)iw < 160u)
            acc = fmaf(wgt[kh*4+kw], bfu2f((unsigned short)KP[ih*160+iw]), acc);
        }
      }
    }
    A1L[i] = gelu_f(acc);
  }
  __syncthreads();
  if (tid < 121){
    int ph = tid/11, pw = tid - ph*11;
    float acc = bia;
    #pragma unroll
    for (int kh=0;kh<4;kh++){
      int ih = ph*4-2+kh;
      if ((unsigned)ih < 41u){
        #pragma unroll
        for (int kw=0;kw<4;kw++){
          int iw = pw*4-2+kw;
          if ((unsigned)iw < 41u)
            acc = fmaf(wgt[kh*4+kw], A1L[ih*41+iw], acc);
        }
      }
    }
    A2L[tid] = gelu_f(acc);
  }
  __syncthreads();
  if (tid < 121){
    int ph = tid/11, pw = tid - ph*11;
    float acc = dwb[c];
    #pragma unroll
    for (int kh=0;kh<3;kh++){
      int ih = ph-1+kh;
      if ((unsigned)ih < 11u){
        #pragma unroll
        for (int kw=0;kw<3;kw++){
          int iw = pw-1+kw;
          if ((unsigned)iw < 11u)
            acc = fmaf(dww[c*9+kh*3+kw], A2L[ih*11+iw], acc);
        }
      }
    }
    T1[(size_t)bc*121 + tid] = acc;
  }
}

// K7: 1x1 dense conv on 11x11 + bias (no act)
__global__ __launch_bounds__(256) void k_calpw(const float* __restrict__ T1,
                                               const float* __restrict__ pww,
                                               const float* __restrict__ pwb,
                                               float* __restrict__ KSo){
  int t = blockIdx.x*256+threadIdx.x;
  if (t >= 16*64*121) return;
  int p  = t % 121;
  int co = (t/121) & 63;
  int b  = t/(121*64);
  const float* Wp = pww + co*64;
  const float* ip = T1 + b*64*121 + p;
  float acc = pwb[co];
  for (int ci=0;ci<64;ci++) acc = fmaf(Wp[ci], ip[ci*121], acc);
  KSo[t] = acc;
}

// K8: gating: logits = meanX @ gate^T, softmax, top-2 scatter
__global__ __launch_bounds__(64) void k_gate(const float* __restrict__ meanX,
                                             const float* __restrict__ gatew,
                                             float* __restrict__ expw){
  __shared__ float lg[64];
  int t = threadIdx.x;
  int b = t>>2, e = t&3;
  const float* g = gatew + e*64;
  const float* m = meanX + b*64;
  float s = 0.f;
  for (int c2=0;c2<64;c2++) s += g[c2]*m[c2];
  lg[t] = s;
  __syncthreads();
  if (e==0){
    float v0=lg[t], v1=lg[t+1], v2=lg[t+2], v3=lg[t+3];
    float mx = fmaxf(fmaxf(v0,v1), fmaxf(v2,v3));
    float p[4];
    p[0]=expf(v0-mx); p[1]=expf(v1-mx); p[2]=expf(v2-mx); p[3]=expf(v3-mx);
    float sum = p[0]+p[1]+p[2]+p[3];
    float inv = 1.0f/sum;
    p[0]*=inv; p[1]*=inv; p[2]*=inv; p[3]*=inv;
    int i1 = 0;
    for (int i=1;i<4;i++) if (p[i] > p[i1]) i1 = i;      // strict > -> lowest idx on tie
    int i2 = -1;
    for (int i=0;i<4;i++){ if (i==i1) continue; if (i2<0 || p[i]>p[i2]) i2 = i; }
    for (int i=0;i<4;i++) expw[b*4+i] = (i==i1||i==i2)? p[i] : 0.f;
  }
}

// K8b: pw3[r][e*5+l]=sum_c P[r][c]*e_w3[e][c][l], pb3[r][e]=sum_c P[r][c]*e_b3[e][c]
__global__ __launch_bounds__(256) void k_pw3(const float* __restrict__ ew3,
                                             const float* __restrict__ eb3,
                                             const float* __restrict__ projw,
                                             float* __restrict__ pw3,
                                             float* __restrict__ pb3){
  int t = blockIdx.x*256+threadIdx.x;
  if (t >= 64*24) return;
  int r = t/24, q = t%24;
  const float* P = projw + r*64;
  if (q < 20){
    int e=q/5, l=q%5;
    float s=0.f;
    for (int c=0;c<64;c++) s = fmaf(P[c], ew3[(e*64+c)*5 + l], s);
    pw3[r*20+q] = s;
  } else {
    int e = q-20;
    float s=0.f;
    for (int c=0;c<64;c++) s = fmaf(P[c], eb3[e*64 + c], s);
    pb3[r*4+e] = s;
  }
}

// K_KK: KK = k0 + bilinear_upsample(KS, 11->160), stored fp8. 8 px/thread.
__global__ __launch_bounds__(256) void k_kk(const bf16* __restrict__ k0,
                                            const float* __restrict__ KSi,
                                            uint8_t* __restrict__ kk8){
  int tt = blockIdx.x*256 + threadIdx.x;   // 3,276,800 total
  int bc = tt / 3200;
  int rr = tt - bc*3200;
  int ph = rr / 20;
  int pw0 = (rr - ph*20) * 8;
  float shf = (ph+0.5f)*0.06875f - 0.5f;   // *11/160
  int ihf = (int)floorf(shf); float th = shf - (float)ihf;
  int i0 = min(max(ihf,0),10), i1 = min(max(ihf+1,0),10);
  const float* ksp = KSi + bc*121;
  size_t base = (size_t)bc*25600 + ph*160 + pw0;
  v8s kv = *reinterpret_cast<const v8s*>(k0 + base);
  unsigned long long o = 0ull;
  #pragma unroll
  for (int j=0;j<8;j++){
    int pw = pw0 + j;
    float swf = (pw+0.5f)*0.06875f - 0.5f;
    int iwf = (int)floorf(swf); float tw = swf - (float)iwf;
    int j0 = min(max(iwf,0),10), j1 = min(max(iwf+1,0),10);
    float v00 = ksp[i0*11+j0], v01 = ksp[i0*11+j1];
    float v10 = ksp[i1*11+j0], v11 = ksp[i1*11+j1];
    float vtop = v00 + tw*(v01-v00);
    float vbot = v10 + tw*(v11-v10);
    float val = bfu2f((unsigned short)kv[j]) + (vtop + th*(vbot-vtop));
    o |= ((unsigned long long)f2e4(val)) << (8*j);
  }
  *reinterpret_cast<unsigned long long*>(kk8 + base) = o;
}

// K9: fused expert bilinear-gated mixing + residual + final 1x1 proj.
// Reads ONLY d_in0 (xsf, kk8, expw, pw3, pb3) + weights; writes f32 d_out.
__global__ __launch_bounds__(256) void k_final(const bf16* __restrict__ xsf,
                                               const uint8_t* __restrict__ kk8,
                                               const float* __restrict__ expw,
                                               const float* __restrict__ pw3,
                                               const float* __restrict__ pb3,
                                               const float* __restrict__ ew1,
                                               const float* __restrict__ eb1,
                                               const float* __restrict__ ew2,
                                               const float* __restrict__ eb2,
                                               const float* __restrict__ projw,
                                               const float* __restrict__ projb,
                                               float* __restrict__ out){
  __shared__ float XS[4096];
  __shared__ float KK[4096];
  __shared__ float PP[1280];
  int bid = blockIdx.x;
  int pt = bid % 400;
  int b  = bid / 400;
  int p0 = pt<<6;
  int tid = threadIdx.x;
  int lane = tid & 63;
  // vectorized staging: 512 chunks of 8 elements
  for (int cw = tid; cw < 512; cw += 256){
    int c = cw >> 3, w0 = (cw & 7) << 3;
    size_t gi = (size_t)(b*64+c)*25600 + p0 + w0;
    v8s xv = *reinterpret_cast<const v8s*>(xsf + gi);
    unsigned long long kv = *reinterpret_cast<const unsigned long long*>(kk8 + gi);
    #pragma unroll
    for (int j=0;j<8;j++){
      XS[(c<<6)+w0+j] = bfu2f((unsigned short)xv[j]);
      KK[(c<<6)+w0+j] = e42f((uint8_t)((kv >> (8*j)) & 0xFF));
    }
  }
  __syncthreads();
  int wv = __builtin_amdgcn_readfirstlane(tid>>6);
  // Phase A: wave wv handles expert e=wv, writes exp_w-scaled p into PP
  {
    int e = wv;
    float a[5], bb[5];
    #pragma unroll
    for (int l=0;l<5;l++) a[l] = eb1[e*5 + l];
    const float* W1 = ew1 + e*5*64;
    for (int c=0;c<64;c++){
      float xv = XS[(c<<6)+lane];
      #pragma unroll
      for (int l=0;l<5;l++) a[l] = fmaf(W1[l*64+c], xv, a[l]);
    }
    #pragma unroll
    for (int l=0;l<5;l++) bb[l] = eb2[e*5 + l];
    const float* W2 = ew2 + e*5*64;
    for (int c=0;c<64;c++){
      float kv = KK[(c<<6)+lane];
      #pragma unroll
      for (int l=0;l<5;l++) bb[l] = fmaf(W2[l*64+c], kv, bb[l]);
    }
    float we = expw[b*4 + e];
    #pragma unroll
    for (int l=0;l<5;l++) PP[(e*5+l)*64 + lane] = we * a[l]*bb[l];
  }
  __syncthreads();
  // Phase B: Y = proj_b + P@bias3 + P@XS + PW3@PP ; wave wv -> rows wv*16..+15
  float ew0 = expw[b*4+0], ewa = expw[b*4+1], ewb = expw[b*4+2], ewc = expw[b*4+3];
  for (int qg=0; qg<4; qg++){
    int r0 = (wv<<4) + (qg<<2);
    float y[4];
    #pragma unroll
    for (int q=0;q<4;q++){
      int r = r0+q;
      y[q] = projb[r] + ew0*pb3[r*4+0] + ewa*pb3[r*4+1] + ewb*pb3[r*4+2] + ewc*pb3[r*4+3];
    }
    const float* Pw = projw + r0*64;
    for (int c=0;c<64;c++){
      float xv = XS[(c<<6)+lane];
      y[0]=fmaf(Pw[c]     ,xv,y[0]);
      y[1]=fmaf(Pw[64+c]  ,xv,y[1]);
      y[2]=fmaf(Pw[128+c] ,xv,y[2]);
      y[3]=fmaf(Pw[192+c] ,xv,y[3]);
    }
    const float* Qw = pw3 + r0*20;
    for (int j=0;j<20;j++){
      float pv = PP[(j<<6)+lane];
      y[0]=fmaf(Qw[j]    ,pv,y[0]);
      y[1]=fmaf(Qw[20+j] ,pv,y[1]);
      y[2]=fmaf(Qw[40+j] ,pv,y[2]);
      y[3]=fmaf(Qw[60+j] ,pv,y[3]);
    }
    #pragma unroll
    for (int q=0;q<4;q++)
      out[(size_t)(b*64+r0+q)*25600 + p0 + lane] = y[q];
  }
}

// ---- scratch layouts (bytes) ----
// d_out (104,857,600 B):
//   xT bf16 [0, 52,428,800)  [k_tr -> k_conv12; then dead -> scratch region]
//     scratch: meanX@0 (4KB, k_zero after conv12), KS@65,536, T1@2,097,152
//   k0 bf16 [52,428,800, 104,857,600)  [conv12 -> k_aggfuse, k_kk]
//   everything dead before k_final overwrites d_out with the f32 result.
// d_in0 / x-buffer (104,857,600 B): x consumed by k_tr ->
//   xs0 bf16 [0, 52,428,800)  [conv12 -> k_sc; dead] ->
//     kk8 fp8 [0, 26,214,400)  [k_kk -> k_final]
//     expw@26,214,400  pw3@26,218,496  pb3@26,226,688
//   xsf bf16 [52,428,800, 104,857,600)  [k_sc -> k_final]
static constexpr size_t OB_XT   = 0;
static constexpr size_t OB_K0   = 52428800;
static constexpr size_t OB_MEAN = 0;
static constexpr size_t OB_KS   = 65536;
static constexpr size_t OB_T1   = 2097152;
static constexpr size_t XB_XS0  = 0;
static constexpr size_t XB_KK8  = 0;
static constexpr size_t XB_EXPW = 26214400;
static constexpr size_t XB_PW3  = 26218496;
static constexpr size_t XB_PB3  = 26226688;
static constexpr size_t XB_XSF  = 52428800;

extern "C" void kernel_launch(void* const* d_in, const int* in_sizes, int n_in,
                              void* d_out, int out_size, void* d_ws, size_t ws_size,
                              hipStream_t stream){
  (void)in_sizes; (void)n_in; (void)out_size; (void)d_ws; (void)ws_size;
  const float* x     = (const float*)d_in[0];
  char* xb           = (char*)d_in[0];     // x dead after k_tr; harness restores each launch
  const float* c1w1  = (const float*)d_in[1];
  const float* c1b1  = (const float*)d_in[2];
  const float* c1w2  = (const float*)d_in[3];
  const float* c1b2  = (const float*)d_in[4];
  const float* aggw  = (const float*)d_in[5];
  const float* aggb  = (const float*)d_in[6];
  const float* dww   = (const float*)d_in[7];
  const float* dwb   = (const float*)d_in[8];
  const float* pww   = (const float*)d_in[9];
  const float* pwb   = (const float*)d_in[10];
  const float* scw1  = (const float*)d_in[11];
  const float* scb1  = (const float*)d_in[12];
  const float* scw2  = (const float*)d_in[13];
  const float* scb2  = (const float*)d_in[14];
  const float* gatew = (const float*)d_in[15];
  const float* ew1   = (const float*)d_in[16];
  const float* eb1   = (const float*)d_in[17];
  const float* ew2   = (const float*)d_in[18];
  const float* eb2   = (const float*)d_in[19];
  const float* ew3   = (const float*)d_in[20];
  const float* eb3   = (const float*)d_in[21];
  const float* projw = (const float*)d_in[22];
  const float* projb = (const float*)d_in[23];

  char* ob = (char*)d_out;
  bf16* xT     = (bf16*)(ob + OB_XT);
  bf16* k0     = (bf16*)(ob + OB_K0);
  float* meanX = (float*)(ob + OB_MEAN);
  float* KS    = (float*)(ob + OB_KS);
  float* T1    = (float*)(ob + OB_T1);
  bf16* xs0    = (bf16*)(xb + XB_XS0);
  uint8_t* kk8 = (uint8_t*)(xb + XB_KK8);
  float* expw  = (float*)(xb + XB_EXPW);
  float* pw3   = (float*)(xb + XB_PW3);
  float* pb3   = (float*)(xb + XB_PB3);
  bf16* xsf    = (bf16*)(xb + XB_XSF);
  float* outp  = (float*)d_out;

  k_tr     <<<2560,     256, 0, stream>>>(x, xT);
  // x fully consumed; x-buffer becomes scratch.
  k_conv12 <<<5120,     256, 0, stream>>>(xT, c1w1, c1b1, c1w2, c1b2, xs0, k0);
  // xT dead; d_out[0,52.4M) becomes scratch.
  k_zero   <<<4,        256, 0, stream>>>(meanX);
  k_sc     <<<12800,    256, 0, stream>>>(xs0, scw1, scb1, scw2, scb2, xsf, meanX);
  // xs0 dead; d_in0[0,52.4M) free for kk8 + small bufs.
  k_aggfuse<<<1024,     256, 0, stream>>>(k0, aggw, aggb, dww, dwb, T1);
  k_calpw  <<<484,      256, 0, stream>>>(T1, pww, pwb, KS);
  k_gate   <<<1,         64, 0, stream>>>(meanX, gatew, expw);
  k_pw3    <<<6,        256, 0, stream>>>(ew3, eb3, projw, pw3, pb3);
  k_kk     <<<12800,    256, 0, stream>>>(k0, KS, kk8);
  // k0 dead; all of d_out dead; k_final writes the f32 result.
  k_final  <<<16*400,   256, 0, stream>>>(xsf, kk8, expw, pw3, pb3,
                                          ew1, eb1, ew2, eb2, projw, projb, outp);
}

// Round 8
// 576.836 us; speedup vs baseline: 1.1219x; 1.1219x over previous
//
#include <hip/hip_runtime.h>
#include <hip/hip_bf16.h>
#include <math.h>
#include <stdint.h>

typedef __hip_bfloat16 bf16;

__device__ __forceinline__ float b2f(bf16 v){ return __bfloat162float(v); }
__device__ __forceinline__ bf16  f2b(float v){ return __float2bfloat16(v); }
__device__ __forceinline__ float gelu_f(float x){ return 0.5f*x*(1.0f+erff(x*0.70710678118654752f)); }
__device__ __forceinline__ float tof(float v){ return v; }
__device__ __forceinline__ float tof(bf16 v){ return __bfloat162float(v); }

// fp8 e4m3 (OCP on gfx950) via HW converts; store value*16 to stay in normal range
#define SC8  16.0f
#define ISC8 0.0625f
__device__ __forceinline__ uint8_t f2e4(float v){
  int r = __builtin_amdgcn_cvt_pk_fp8_f32(v*SC8, v*SC8, 0, false);
  return (uint8_t)(r & 0xFF);
}
__device__ __forceinline__ float e42f(uint8_t b){
  return __builtin_amdgcn_cvt_f32_fp8((int)b, 0) * ISC8;
}

// MFMA types: gfx950 v_mfma_f32_16x16x32_bf16 takes 8 x __bf16 vectors (LLVM V8y)
typedef __bf16 bf16x8 __attribute__((ext_vector_type(8)));
typedef float  f32x4  __attribute__((ext_vector_type(4)));
typedef short  v8s    __attribute__((ext_vector_type(8)));
union Frag { bf16x8 v; unsigned short u[8]; };

__device__ __forceinline__ unsigned short bfb(float v){
  union { bf16 h; unsigned short u; } cv; cv.h = f2b(v); return cv.u;
}
__device__ __forceinline__ float bfu2f(unsigned short u){
  union { float f; unsigned u32; } x; x.u32 = ((unsigned)u) << 16; return x.f;
}
__device__ __forceinline__ bf16x8 ldsb8(const short* p){
  return *reinterpret_cast<const bf16x8*>(p);
}
// k_tr internal LDS swizzle (multiple of 8 -> preserves in-order 8-ci chunks)
__device__ __forceinline__ int SW8(int w){ return ((w ^ (w >> 3)) & 7) << 3; }

// ---- problem constants: B=16, C=64, H=W=160, HW=25600, E=4, L=5 ----
// ---- ALL inputs/outputs are FLOAT32 (per reference setup_inputs). ----
// ---- ZERO d_ws usage. Scratch: d_out (104,857,600 B) + x-buffer (104,857,600 B).

// K_TR: x (NCHW f32) -> xT (NHWC bf16). Block = (b,h). LDS transpose.
__global__ __launch_bounds__(256) void k_tr(const float* __restrict__ x,
                                            bf16* __restrict__ xT){
  __shared__ __align__(16) short LT[160*64];   // [w][ci^SW8(w)]  (40,960 B)
  int bid = blockIdx.x;
  int h = bid % 160;
  int b = bid / 160;
  int tid = threadIdx.x;
  // stage-in: 1280 pair-quads: (ci0 even, w4): read 2 float4, pack 4 b32 writes
  #pragma unroll
  for (int i=0;i<5;i++){
    int q = tid + i*256;               // < 1280 always
    int ci0 = (q/40)*2;
    int w4  = (q - (q/40)*40)*4;
    const float* pa = x + (((b*64 + ci0)*160 + h)*160) + w4;
    float4 fa = *reinterpret_cast<const float4*>(pa);
    float4 fb = *reinterpret_cast<const float4*>(pa + 25600);
    float va[4] = {fa.x, fa.y, fa.z, fa.w};
    float vb[4] = {fb.x, fb.y, fb.z, fb.w};
    #pragma unroll
    for (int j=0;j<4;j++){
      int w = w4 + j;
      unsigned pk = (unsigned)bfb(va[j]) | ((unsigned)bfb(vb[j]) << 16);
      int slot = w*64 + (ci0 ^ SW8(w));
      *reinterpret_cast<unsigned*>(&LT[slot]) = pk;
    }
  }
  __syncthreads();
  // stage-out: 1280 chunks (w, ci0 mult 8): b128 LDS read -> b128 global store
  bf16* dst = xT + ((size_t)(b*160 + h))*160*64;
  #pragma unroll
  for (int i=0;i<5;i++){
    int k = tid + i*256;               // < 1280
    int w = k >> 3;
    int ci0 = (k & 7) << 3;
    v8s v = *reinterpret_cast<const v8s*>(&LT[w*64 + (ci0 ^ SW8(w))]);
    *reinterpret_cast<v8s*>(dst + w*64 + ci0) = v;
  }
}

// K_ZERO: zero meanX (1024 f32). No runtime APIs in kernel_launch (graph-capture).
__global__ __launch_bounds__(256) void k_zero(float* __restrict__ p){
  p[blockIdx.x*256 + threadIdx.x] = 0.f;
}

// K1: FUSED 3x3 conv (64->64)+bias+gelu -> 1x1 conv (64->128)+bias + shuffle split,
// implicit-GEMM bf16 MFMA (16x16x32). STRIP version: block = (b, half, 5-row strip),
// 4 waves. Weight gather amortized 5x; rolling 4-slab halo buffer cuts staging 2.1x;
// next-row loads issued to regs before conv1, written to LDS after (latency hidden).
// MFMA core + epilogue arithmetic identical to the verified round-4/7 kernel.
__global__ __launch_bounds__(256) void k_conv12(const bf16* __restrict__ xT,
                                                const float* __restrict__ w1,
                                                const float* __restrict__ b1,
                                                const float* __restrict__ w2,
                                                const float* __restrict__ b2,
                                                bf16* __restrict__ xs0,
                                                bf16* __restrict__ k0){
  __shared__ __align__(16) short Xs[4*5376];  // 4 slabs x 84 cols x 64 ci (43,008 B)
  __shared__ __align__(16) short H1[5120];    // 80*64 (10,240 B)
  int bid = blockIdx.x;
  int strip = bid & 31;
  int half  = (bid >> 5) & 1;
  int b     = bid >> 6;
  int h0 = strip * 5;
  int w0 = half * 80;
  int tid = threadIdx.x;
  int lane = tid & 63;
  int wv = tid >> 6;
  int c = lane & 15;     // pixel-in-group / A-row
  int g = lane >> 4;     // k-group
  const bf16* xTb = xT + (size_t)b*160*160*64;

  // ---- weight gather (once per block, amortized over 5 rows) ----
  Frag wf[18];
  {
    int co = wv*16 + c;
    const float* wbase = w1 + co*576 + g*72;   // + kk*288 + e*9 + r*3 + s
    #pragma unroll
    for (int r=0;r<3;r++){
      #pragma unroll
      for (int s=0;s<3;s++){
        #pragma unroll
        for (int kk=0;kk<2;kk++){
          Frag f;
          #pragma unroll
          for (int e=0;e<8;e++)
            f.u[e] = bfb(wbase[kk*288 + e*9 + r*3 + s]);
          wf[(r*3+s)*2+kk] = f;
        }
      }
    }
  }
  Frag w2f[4];
  {
    #pragma unroll
    for (int j=0;j<2;j++){
      #pragma unroll
      for (int kk=0;kk<2;kk++){
        const float* wp = w2 + (wv*32 + j*16 + c)*64 + kk*32 + g*8;
        Frag f;
        #pragma unroll
        for (int e=0;e<8;e++) f.u[e] = bfb(wp[e]);
        w2f[j*2+kk] = f;
      }
    }
  }
  float bb1r[4];
  {
    const float* bp = b1 + wv*16 + g*4;
    #pragma unroll
    for (int r=0;r<4;r++) bb1r[r] = bp[r];
  }
  float bb2r[2][4];
  #pragma unroll
  for (int j=0;j<2;j++){
    const float* bp = b2 + wv*32 + j*16 + g*4;
    #pragma unroll
    for (int r=0;r<4;r++) bb2r[j][r] = bp[r];
  }
  // store channel-bases (h-independent); shuffled split: new ch = (o%64)*2 + o/64
  int cb[2][4]; int flg[2][4];
  #pragma unroll
  for (int j=0;j<2;j++){
    #pragma unroll
    for (int r=0;r<4;r++){
      int o = wv*32 + j*16 + g*4 + r;
      int n2 = ((o & 63) << 1) | (o >> 6);
      if (n2 < 64){ cb[j][r] = (b*64 + n2)*25600 + w0 + c;        flg[j][r] = 1; }
      else        { cb[j][r] = (b*64 + (n2-64))*25600 + w0 + c;   flg[j][r] = 0; }
    }
  }
  // B-frag col/swizzle offsets (slab-base added per row)
  int bB[3][2];
  #pragma unroll
  for (int s=0;s<3;s++){
    #pragma unroll
    for (int kk=0;kk<2;kk++)
      bB[s][kk] = (c + s)*64 + ((kk*32 + g*8) ^ (((c + s) & 7) << 3));
  }
  int bH0 = c*64 + ((g*8)      ^ ((c & 7) << 3));
  int bH1 = c*64 + ((32 + g*8) ^ ((c & 7) << 3));

  // ---- prologue: stage slabs for rows h0-1, h0, h0+1 (slot = (gh+1)&3) ----
  #pragma unroll
  for (int it=0; it<8; ++it){
    int q = tid + it*256;
    if (q < 2016){
      int r   = q / 672;            // 0..2 -> gh = h0-1+r
      int rem = q - r*672;
      int col = rem >> 3;
      int ci0 = (rem & 7) << 3;
      int gh  = h0 - 1 + r;
      int gw  = w0 - 1 + col;
      v8s val = {0,0,0,0,0,0,0,0};
      if ((unsigned)gh < 160u && (unsigned)gw < 160u)
        val = *reinterpret_cast<const v8s*>(xTb + (gh*160 + gw)*64 + ci0);
      int slot = (gh + 1) & 3;
      *reinterpret_cast<v8s*>(&Xs[slot*5376 + col*64 + (ci0 ^ ((col & 7) << 3))]) = val;
    }
  }
  __syncthreads();

  // ---- 5-row loop ----
  #pragma unroll 1
  for (int row=0; row<5; ++row){
    int h = h0 + row;
    // issue next-slab loads (row h+2) into regs; write to LDS after conv1
    v8s stv[3]; int stq[3];
    #pragma unroll
    for (int it=0; it<3; ++it){
      int q = tid + it*256;
      stq[it] = (q < 672 && row < 4) ? q : -1;
      v8s val = {0,0,0,0,0,0,0,0};
      if (stq[it] >= 0){
        int col = q >> 3;
        int ci0 = (q & 7) << 3;
        int gh  = h + 2;
        int gw  = w0 - 1 + col;
        if (gh < 160 && (unsigned)gw < 160u)
          val = *reinterpret_cast<const v8s*>(xTb + (gh*160 + gw)*64 + ci0);
      }
      stv[it] = val;
    }
    // conv1: 9 per-tap GEMMs, K=64 (2 halves) -> gelu -> H1
    int sb0 = ((h  ) & 3) * 5376;   // tap row r=0 -> input row h-1
    int sb1 = ((h+1) & 3) * 5376;
    int sb2 = ((h+2) & 3) * 5376;
    #pragma unroll 1
    for (int n=0;n<5;++n){
      f32x4 acc0 = {0.f,0.f,0.f,0.f};
      f32x4 acc1 = {0.f,0.f,0.f,0.f};
      #pragma unroll
      for (int r=0;r<3;r++){
        int base = (r==0?sb0:(r==1?sb1:sb2)) + n*1024;
        #pragma unroll
        for (int s=0;s<3;s++){
          bf16x8 bf0 = ldsb8(&Xs[bB[s][0] + base]);
          bf16x8 bf1 = ldsb8(&Xs[bB[s][1] + base]);
          int t = (r*3 + s)*2;
          acc0 = __builtin_amdgcn_mfma_f32_16x16x32_bf16(wf[t].v,   bf0, acc0, 0, 0, 0);
          acc1 = __builtin_amdgcn_mfma_f32_16x16x32_bf16(wf[t+1].v, bf1, acc1, 0, 0, 0);
        }
      }
      // D: lane -> px = n*16+c, ch = 16wv + 4g + r
      unsigned long long pk = 0ull;
      #pragma unroll
      for (int r=0;r<4;r++){
        float v = gelu_f(acc0[r] + acc1[r] + bb1r[r]);
        pk |= ((unsigned long long)bfb(v)) << (16*r);
      }
      int eH = (n*16 + c)*64 + ((wv*16 + g*4) ^ ((c & 7) << 3));
      *reinterpret_cast<unsigned long long*>(&H1[eH]) = pk;
    }
    // write staged slab (slot (h+3)&3 — disjoint from slots read above)
    {
      int slot = (h + 3) & 3;
      #pragma unroll
      for (int it=0; it<3; ++it){
        if (stq[it] >= 0){
          int col = stq[it] >> 3;
          int ci0 = (stq[it] & 7) << 3;
          *reinterpret_cast<v8s*>(&Xs[slot*5376 + col*64 + (ci0 ^ ((col & 7) << 3))]) = stv[it];
        }
      }
    }
    __syncthreads();   // H1 visible + staged slab ready
    // conv2: 1x1, K=64, wave owns out ch [32wv,32wv+32), shuffle-split store
    int posb = h*160;
    #pragma unroll 1
    for (int n=0;n<5;++n){
      bf16x8 hh0 = ldsb8(&H1[bH0 + n*1024]);
      bf16x8 hh1 = ldsb8(&H1[bH1 + n*1024]);
      #pragma unroll
      for (int j=0;j<2;j++){
        f32x4 acc = {0.f,0.f,0.f,0.f};
        acc = __builtin_amdgcn_mfma_f32_16x16x32_bf16(w2f[j*2].v,   hh0, acc, 0, 0, 0);
        acc = __builtin_amdgcn_mfma_f32_16x16x32_bf16(w2f[j*2+1].v, hh1, acc, 0, 0, 0);
        #pragma unroll
        for (int r=0;r<4;r++){
          float v = acc[r] + bb2r[j][r];
          bf16 bv = f2b(v);
          int addr = cb[j][r] + posb + n*16;
          if (flg[j][r]) xs0[addr] = bv;
          else           k0 [addr] = bv;
        }
      }
    }
    __syncthreads();   // H1 free for next row
  }
}

// K3: separable depthwise (1x3 then 3x1) + gelu, 8 px/thread, FUSED mean:
// every wave is bc-uniform (3200 px/bc = 50 waves) -> shfl-reduce + 1 atomic/wave.
__global__ __launch_bounds__(256) void k_sc(const bf16* __restrict__ xs0,
                                            const float* __restrict__ scw1,
                                            const float* __restrict__ scb1,
                                            const float* __restrict__ scw2,
                                            const float* __restrict__ scb2,
                                            bf16* __restrict__ xsf,
                                            float* __restrict__ meanX){
  int t = blockIdx.x*256 + threadIdx.x;       // 3,276,800 total
  int w8 = (t % 20) * 8;
  int r2 = t / 20;
  int h  = r2 % 160;
  int bc = r2 / 160;
  int c  = bc & 63;
  const bf16* plane = xs0 + (size_t)bc*25600;
  float w1a = scw1[c*3], w1b = scw1[c*3+1], w1c = scw1[c*3+2];
  float b1  = scb1[c];
  float w2a = scw2[c*3], w2b = scw2[c*3+1], w2c = scw2[c*3+2];
  float b2v = scb2[c];
  float acc[8];
  #pragma unroll
  for (int j=0;j<8;j++) acc[j] = b2v;
  #pragma unroll
  for (int dh=0; dh<3; dh++){
    int hh = h-1+dh;
    if ((unsigned)hh < 160u){
      const bf16* row = plane + hh*160;
      float wnd[10];
      v8s mv = *reinterpret_cast<const v8s*>(row + w8);
      #pragma unroll
      for (int j=0;j<8;j++) wnd[j+1] = bfu2f((unsigned short)mv[j]);
      wnd[0] = (w8 > 0)   ? b2f(row[w8-1]) : 0.f;
      wnd[9] = (w8 < 152) ? b2f(row[w8+8]) : 0.f;
      float w2h = (dh==0)?w2a:((dh==1)?w2b:w2c);
      #pragma unroll
      for (int j=0;j<8;j++){
        float inner = fmaf(w1a, wnd[j], fmaf(w1b, wnd[j+1], fmaf(w1c, wnd[j+2], b1)));
        acc[j] = fmaf(w2h, inner, acc[j]);
      }
    }
  }
  v8s o;
  float ls = 0.f;
  #pragma unroll
  for (int j=0;j<8;j++){
    unsigned short ub = bfb(gelu_f(acc[j]));
    o[j] = (short)ub;
    ls += bfu2f(ub);            // sum the bf16-rounded value (matches old k_mean)
  }
  *reinterpret_cast<v8s*>(xsf + (size_t)bc*25600 + h*160 + w8) = o;
  // wave reduction (bc uniform across the wave: 3200 threads per bc, 3200%64==0)
  #pragma unroll
  for (int off=32; off>0; off>>=1) ls += __shfl_down(ls, off);
  if ((threadIdx.x & 63) == 0) atomicAdd(&meanX[bc], ls*(1.0f/25600.0f));
}

// K4/K5: depthwise 4x4 stride4 pad2 + bias + gelu
template<typename Tin>
__global__ __launch_bounds__(256) void k_agg(const Tin* __restrict__ in,
                                             const float* __restrict__ aggw,
                                             const float* __restrict__ aggb,
                                             float* __restrict__ out,
                                             int IH, int OH, int total){
  int t = blockIdx.x*256+threadIdx.x;
  if (t >= total) return;
  int ow = t % OH;
  int oh = (t/OH) % OH;
  int c  = (t/(OH*OH)) & 63;
  int bc = t/(OH*OH);
  const Tin* ip = in + (size_t)bc*IH*IH;
  const float* Wp = aggw + c*16;
  float acc = aggb[c];
  #pragma unroll
  for (int kh=0;kh<4;kh++){
    int ih = oh*4 - 2 + kh;
    if ((unsigned)ih < (unsigned)IH){
      #pragma unroll
      for (int kw=0;kw<4;kw++){
        int iw = ow*4 - 2 + kw;
        if ((unsigned)iw < (unsigned)IH)
          acc = fmaf(Wp[kh*4+kw], tof(ip[ih*IH+iw]), acc);
      }
    }
  }
  out[t] = gelu_f(acc);
}

// K6: depthwise 3x3 pad1 + bias on 11x11 (no act)
__global__ __launch_bounds__(256) void k_caldw(const float* __restrict__ A2,
                                               const float* __restrict__ dww,
                                               const float* __restrict__ dwb,
                                               float* __restrict__ T1){
  int t = blockIdx.x*256+threadIdx.x;
  if (t >= 16*64*121) return;
  int pw = t % 11;
  int ph = (t/11) % 11;
  int c  = (t/121) & 63;
  int bc = t/121;
  const float* ip = A2 + bc*121;
  const float* Wp = dww + c*9;
  float acc = dwb[c];
  #pragma unroll
  for (int kh=0;kh<3;kh++){
    int ih = ph-1+kh;
    if ((unsigned)ih < 11u){
      #pragma unroll
      for (int kw=0;kw<3;kw++){
        int iw = pw-1+kw;
        if ((unsigned)iw < 11u)
          acc = fmaf(Wp[kh*3+kw], ip[ih*11+iw], acc);
      }
    }
  }
  T1[t] = acc;
}

// K7: 1x1 dense conv on 11x11 + bias (no act)
__global__ __launch_bounds__(256) void k_calpw(const float* __restrict__ T1,
                                               const float* __restrict__ pww,
                                               const float* __restrict__ pwb,
                                               float* __restrict__ KSo){
  int t = blockIdx.x*256+threadIdx.x;
  if (t >= 16*64*121) return;
  int p  = t % 121;
  int co = (t/121) & 63;
  int b  = t/(121*64);
  const float* Wp = pww + co*64;
  const float* ip = T1 + b*64*121 + p;
  float acc = pwb[co];
  for (int ci=0;ci<64;ci++) acc = fmaf(Wp[ci], ip[ci*121], acc);
  KSo[t] = acc;
}

// K8: gating: logits = meanX @ gate^T, softmax, top-2 scatter
__global__ __launch_bounds__(64) void k_gate(const float* __restrict__ meanX,
                                             const float* __restrict__ gatew,
                                             float* __restrict__ expw){
  __shared__ float lg[64];
  int t = threadIdx.x;
  int b = t>>2, e = t&3;
  const float* g = gatew + e*64;
  const float* m = meanX + b*64;
  float s = 0.f;
  for (int c2=0;c2<64;c2++) s += g[c2]*m[c2];
  lg[t] = s;
  __syncthreads();
  if (e==0){
    float v0=lg[t], v1=lg[t+1], v2=lg[t+2], v3=lg[t+3];
    float mx = fmaxf(fmaxf(v0,v1), fmaxf(v2,v3));
    float p[4];
    p[0]=expf(v0-mx); p[1]=expf(v1-mx); p[2]=expf(v2-mx); p[3]=expf(v3-mx);
    float sum = p[0]+p[1]+p[2]+p[3];
    float inv = 1.0f/sum;
    p[0]*=inv; p[1]*=inv; p[2]*=inv; p[3]*=inv;
    int i1 = 0;
    for (int i=1;i<4;i++) if (p[i] > p[i1]) i1 = i;      // strict > -> lowest idx on tie
    int i2 = -1;
    for (int i=0;i<4;i++){ if (i==i1) continue; if (i2<0 || p[i]>p[i2]) i2 = i; }
    for (int i=0;i<4;i++) expw[b*4+i] = (i==i1||i==i2)? p[i] : 0.f;
  }
}

// K8b: pw3[r][e*5+l]=sum_c P[r][c]*e_w3[e][c][l], pb3[r][e]=sum_c P[r][c]*e_b3[e][c]
__global__ __launch_bounds__(256) void k_pw3(const float* __restrict__ ew3,
                                             const float* __restrict__ eb3,
                                             const float* __restrict__ projw,
                                             float* __restrict__ pw3,
                                             float* __restrict__ pb3){
  int t = blockIdx.x*256+threadIdx.x;
  if (t >= 64*24) return;
  int r = t/24, q = t%24;
  const float* P = projw + r*64;
  if (q < 20){
    int e=q/5, l=q%5;
    float s=0.f;
    for (int c=0;c<64;c++) s = fmaf(P[c], ew3[(e*64+c)*5 + l], s);
    pw3[r*20+q] = s;
  } else {
    int e = q-20;
    float s=0.f;
    for (int c=0;c<64;c++) s = fmaf(P[c], eb3[e*64 + c], s);
    pb3[r*4+e] = s;
  }
}

// K_KK: KK = k0 + bilinear_upsample(KS, 11->160), stored fp8. 8 px/thread.
__global__ __launch_bounds__(256) void k_kk(const bf16* __restrict__ k0,
                                            const float* __restrict__ KSi,
                                            uint8_t* __restrict__ kk8){
  int tt = blockIdx.x*256 + threadIdx.x;   // 3,276,800 total
  int bc = tt / 3200;
  int rr = tt - bc*3200;
  int ph = rr / 20;
  int pw0 = (rr - ph*20) * 8;
  float shf = (ph+0.5f)*0.06875f - 0.5f;   // *11/160
  int ihf = (int)floorf(shf); float th = shf - (float)ihf;
  int i0 = min(max(ihf,0),10), i1 = min(max(ihf+1,0),10);
  const float* ksp = KSi + bc*121;
  size_t base = (size_t)bc*25600 + ph*160 + pw0;
  v8s kv = *reinterpret_cast<const v8s*>(k0 + base);
  unsigned long long o = 0ull;
  #pragma unroll
  for (int j=0;j<8;j++){
    int pw = pw0 + j;
    float swf = (pw+0.5f)*0.06875f - 0.5f;
    int iwf = (int)floorf(swf); float tw = swf - (float)iwf;
    int j0 = min(max(iwf,0),10), j1 = min(max(iwf+1,0),10);
    float v00 = ksp[i0*11+j0], v01 = ksp[i0*11+j1];
    float v10 = ksp[i1*11+j0], v11 = ksp[i1*11+j1];
    float vtop = v00 + tw*(v01-v00);
    float vbot = v10 + tw*(v11-v10);
    float val = bfu2f((unsigned short)kv[j]) + (vtop + th*(vbot-vtop));
    o |= ((unsigned long long)f2e4(val)) << (8*j);
  }
  *reinterpret_cast<unsigned long long*>(kk8 + base) = o;
}

// K9: fused expert bilinear-gated mixing + residual + final 1x1 proj.
// Reads ONLY d_in0 (xsf, kk8, expw, pw3, pb3) + weights; writes f32 d_out.
__global__ __launch_bounds__(256) void k_final(const bf16* __restrict__ xsf,
                                               const uint8_t* __restrict__ kk8,
                                               const float* __restrict__ expw,
                                               const float* __restrict__ pw3,
                                               const float* __restrict__ pb3,
                                               const float* __restrict__ ew1,
                                               const float* __restrict__ eb1,
                                               const float* __restrict__ ew2,
                                               const float* __restrict__ eb2,
                                               const float* __restrict__ projw,
                                               const float* __restrict__ projb,
                                               float* __restrict__ out){
  __shared__ float XS[4096];
  __shared__ float KK[4096];
  __shared__ float PP[1280];
  int bid = blockIdx.x;
  int pt = bid % 400;
  int b  = bid / 400;
  int p0 = pt<<6;
  int tid = threadIdx.x;
  int lane = tid & 63;
  // vectorized staging: 512 chunks of 8 elements
  for (int cw = tid; cw < 512; cw += 256){
    int c = cw >> 3, w0 = (cw & 7) << 3;
    size_t gi = (size_t)(b*64+c)*25600 + p0 + w0;
    v8s xv = *reinterpret_cast<const v8s*>(xsf + gi);
    unsigned long long kv = *reinterpret_cast<const unsigned long long*>(kk8 + gi);
    #pragma unroll
    for (int j=0;j<8;j++){
      XS[(c<<6)+w0+j] = bfu2f((unsigned short)xv[j]);
      KK[(c<<6)+w0+j] = e42f((uint8_t)((kv >> (8*j)) & 0xFF));
    }
  }
  __syncthreads();
  int wv = __builtin_amdgcn_readfirstlane(tid>>6);
  // Phase A: wave wv handles expert e=wv, writes exp_w-scaled p into PP
  {
    int e = wv;
    float a[5], bb[5];
    #pragma unroll
    for (int l=0;l<5;l++) a[l] = eb1[e*5 + l];
    const float* W1 = ew1 + e*5*64;
    for (int c=0;c<64;c++){
      float xv = XS[(c<<6)+lane];
      #pragma unroll
      for (int l=0;l<5;l++) a[l] = fmaf(W1[l*64+c], xv, a[l]);
    }
    #pragma unroll
    for (int l=0;l<5;l++) bb[l] = eb2[e*5 + l];
    const float* W2 = ew2 + e*5*64;
    for (int c=0;c<64;c++){
      float kv = KK[(c<<6)+lane];
      #pragma unroll
      for (int l=0;l<5;l++) bb[l] = fmaf(W2[l*64+c], kv, bb[l]);
    }
    float we = expw[b*4 + e];
    #pragma unroll
    for (int l=0;l<5;l++) PP[(e*5+l)*64 + lane] = we * a[l]*bb[l];
  }
  __syncthreads();
  // Phase B: Y = proj_b + P@bias3 + P@XS + PW3@PP ; wave wv -> rows wv*16..+15
  float ew0 = expw[b*4+0], ewa = expw[b*4+1], ewb = expw[b*4+2], ewc = expw[b*4+3];
  for (int qg=0; qg<4; qg++){
    int r0 = (wv<<4) + (qg<<2);
    float y[4];
    #pragma unroll
    for (int q=0;q<4;q++){
      int r = r0+q;
      y[q] = projb[r] + ew0*pb3[r*4+0] + ewa*pb3[r*4+1] + ewb*pb3[r*4+2] + ewc*pb3[r*4+3];
    }
    const float* Pw = projw + r0*64;
    for (int c=0;c<64;c++){
      float xv = XS[(c<<6)+lane];
      y[0]=fmaf(Pw[c]     ,xv,y[0]);
      y[1]=fmaf(Pw[64+c]  ,xv,y[1]);
      y[2]=fmaf(Pw[128+c] ,xv,y[2]);
      y[3]=fmaf(Pw[192+c] ,xv,y[3]);
    }
    const float* Qw = pw3 + r0*20;
    for (int j=0;j<20;j++){
      float pv = PP[(j<<6)+lane];
      y[0]=fmaf(Qw[j]    ,pv,y[0]);
      y[1]=fmaf(Qw[20+j] ,pv,y[1]);
      y[2]=fmaf(Qw[40+j] ,pv,y[2]);
      y[3]=fmaf(Qw[60+j] ,pv,y[3]);
    }
    #pragma unroll
    for (int q=0;q<4;q++)
      out[(size_t)(b*64+r0+q)*25600 + p0 + lane] = y[q];
  }
}

// ---- scratch layouts (bytes) ----
// d_out (104,857,600 B):
//   xT bf16 [0, 52,428,800)  [k_tr -> k_conv12; then dead -> scratch region]
//     scratch: meanX@0 (4KB, k_zero after conv12), KS@65,536, A2@1,048,576,
//              T1@2,097,152, A1@4,194,304 (+6,885,376 -> ends 11,079,680)
//   k0 bf16 [52,428,800, 104,857,600)  [conv12 -> k_agg1, k_kk]
//   everything dead before k_final overwrites d_out with the f32 result.
// d_in0 / x-buffer (104,857,600 B): x consumed by k_tr ->
//   xs0 bf16 [0, 52,428,800)  [conv12 -> k_sc; dead] ->
//     kk8 fp8 [0, 26,214,400)  [k_kk -> k_final]
//     expw@26,214,400  pw3@26,218,496  pb3@26,226,688
//   xsf bf16 [52,428,800, 104,857,600)  [k_sc -> k_final]
static constexpr size_t OB_XT   = 0;
static constexpr size_t OB_K0   = 52428800;
static constexpr size_t OB_MEAN = 0;
static constexpr size_t OB_KS   = 65536;
static constexpr size_t OB_A2   = 1048576;
static constexpr size_t OB_T1   = 2097152;
static constexpr size_t OB_A1   = 4194304;
static constexpr size_t XB_XS0  = 0;
static constexpr size_t XB_KK8  = 0;
static constexpr size_t XB_EXPW = 26214400;
static constexpr size_t XB_PW3  = 26218496;
static constexpr size_t XB_PB3  = 26226688;
static constexpr size_t XB_XSF  = 52428800;

extern "C" void kernel_launch(void* const* d_in, const int* in_sizes, int n_in,
                              void* d_out, int out_size, void* d_ws, size_t ws_size,
                              hipStream_t stream){
  (void)in_sizes; (void)n_in; (void)out_size; (void)d_ws; (void)ws_size;
  const float* x     = (const float*)d_in[0];
  char* xb           = (char*)d_in[0];     // x dead after k_tr; harness restores each launch
  const float* c1w1  = (const float*)d_in[1];
  const float* c1b1  = (const float*)d_in[2];
  const float* c1w2  = (const float*)d_in[3];
  const float* c1b2  = (const float*)d_in[4];
  const float* aggw  = (const float*)d_in[5];
  const float* aggb  = (const float*)d_in[6];
  const float* dww   = (const float*)d_in[7];
  const float* dwb   = (const float*)d_in[8];
  const float* pww   = (const float*)d_in[9];
  const float* pwb   = (const float*)d_in[10];
  const float* scw1  = (const float*)d_in[11];
  const float* scb1  = (const float*)d_in[12];
  const float* scw2  = (const float*)d_in[13];
  const float* scb2  = (const float*)d_in[14];
  const float* gatew = (const float*)d_in[15];
  const float* ew1   = (const float*)d_in[16];
  const float* eb1   = (const float*)d_in[17];
  const float* ew2   = (const float*)d_in[18];
  const float* eb2   = (const float*)d_in[19];
  const float* ew3   = (const float*)d_in[20];
  const float* eb3   = (const float*)d_in[21];
  const float* projw = (const float*)d_in[22];
  const float* projb = (const float*)d_in[23];

  char* ob = (char*)d_out;
  bf16* xT     = (bf16*)(ob + OB_XT);
  bf16* k0     = (bf16*)(ob + OB_K0);
  float* meanX = (float*)(ob + OB_MEAN);
  float* KS    = (float*)(ob + OB_KS);
  float* A2    = (float*)(ob + OB_A2);
  float* T1    = (float*)(ob + OB_T1);
  float* A1    = (float*)(ob + OB_A1);
  bf16* xs0    = (bf16*)(xb + XB_XS0);
  uint8_t* kk8 = (uint8_t*)(xb + XB_KK8);
  float* expw  = (float*)(xb + XB_EXPW);
  float* pw3   = (float*)(xb + XB_PW3);
  float* pb3   = (float*)(xb + XB_PB3);
  bf16* xsf    = (bf16*)(xb + XB_XSF);
  float* outp  = (float*)d_out;

  k_tr     <<<2560,     256, 0, stream>>>(x, xT);
  // x fully consumed; x-buffer becomes scratch.
  k_conv12 <<<1024,     256, 0, stream>>>(xT, c1w1, c1b1, c1w2, c1b2, xs0, k0);
  // xT dead; d_out[0,52.4M) becomes scratch.
  k_zero   <<<4,        256, 0, stream>>>(meanX);
  k_sc     <<<12800,    256, 0, stream>>>(xs0, scw1, scb1, scw2, scb2, xsf, meanX);
  // xs0 dead; d_in0[0,52.4M) free for kk8 + small bufs.
  k_agg<bf16> <<<6724,  256, 0, stream>>>(k0, aggw, aggb, A1, 160, 41, 16*64*41*41);
  k_agg<float><<<484,   256, 0, stream>>>(A1, aggw, aggb, A2, 41, 11, 16*64*11*11);
  k_caldw  <<<484,      256, 0, stream>>>(A2, dww, dwb, T1);
  k_calpw  <<<484,      256, 0, stream>>>(T1, pww, pwb, KS);
  k_gate   <<<1,         64, 0, stream>>>(meanX, gatew, expw);
  k_pw3    <<<6,        256, 0, stream>>>(ew3, eb3, projw, pw3, pb3);
  k_kk     <<<12800,    256, 0, stream>>>(k0, KS, kk8);
  // k0 dead; all of d_out dead; k_final writes the f32 result.
  k_final  <<<16*400,   256, 0, stream>>>(xsf, kk8, expw, pw3, pb3,
                                          ew1, eb1, ew2, eb2, projw, projb, outp);
}